// Round 3
// baseline (720.461 us; speedup 1.0000x reference)
//
#include <hip/hip_runtime.h>
#include <math.h>

#define NB 8
#define NN 2048
#define SCALE 20.0f   // 1 / 0.05
#define RPB 8                // rows per block (= per chunk)
#define CH  (NN / RPB)       // 256 chunks per matrix

typedef float v4f __attribute__((ext_vector_type(4)));

__device__ __forceinline__ float wave_max(float x) {
#pragma unroll
    for (int off = 32; off >= 1; off >>= 1)
        x = fmaxf(x, __shfl_xor(x, off, 64));
    return x;
}
__device__ __forceinline__ float wave_sum(float x) {
#pragma unroll
    for (int off = 32; off >= 1; off >>= 1)
        x += __shfl_xor(x, off, 64);
    return x;
}

// ---------------- fused path ----------------
// Block (256 thr, 4 waves) owns one chunk of 8 rows. Wave w owns a 512-col
// stripe. Per row: wave-local (m,S) -> LDS -> u_r = M + log(sum S_w e^{m_w-M});
// column partial s[c] += e[c] * e^{m_w-M}/T  (== exp(x - u_r)).
__global__ __launch_bounds__(256, 6) void fused_iter(const float* __restrict__ A,
                                                     const float* __restrict__ v,
                                                     float* __restrict__ u,
                                                     float* __restrict__ ps) {
    const int w     = threadIdx.x >> 6;          // wave -> column stripe
    const int lane  = threadIdx.x & 63;
    const int b     = blockIdx.x >> 8;           // / CH
    const int chunk = blockIdx.x & (CH - 1);
    const int row0  = chunk * RPB;
    const int idx0  = (w << 7) + lane;           // float4 index within row
    const int idx1  = idx0 + 64;

    const float4* v4 = (const float4*)(v + (size_t)b * NN);
    const float4 vv0 = v4[idx0];
    const float4 vv1 = v4[idx1];

    const float4* Ab = (const float4*)(A + ((size_t)b * NN + row0) * NN);
    const int RS = NN / 4;                       // row stride in float4

    __shared__ float lm[RPB][4];
    __shared__ float lsum[RPB][4];

    float s[8];
#pragma unroll
    for (int i = 0; i < 8; ++i) s[i] = 0.f;

    float4 a0 = Ab[idx0];
    float4 a1 = Ab[idx1];

#pragma unroll
    for (int r = 0; r < RPB; ++r) {
        const int rn = (r + 1 < RPB) ? r + 1 : r;
        float4 na0 = Ab[rn * RS + idx0];         // prefetch next row
        float4 na1 = Ab[rn * RS + idx1];

        float x[8];
        x[0] = fmaf(a0.x, SCALE, -vv0.x);
        x[1] = fmaf(a0.y, SCALE, -vv0.y);
        x[2] = fmaf(a0.z, SCALE, -vv0.z);
        x[3] = fmaf(a0.w, SCALE, -vv0.w);
        x[4] = fmaf(a1.x, SCALE, -vv1.x);
        x[5] = fmaf(a1.y, SCALE, -vv1.y);
        x[6] = fmaf(a1.z, SCALE, -vv1.z);
        x[7] = fmaf(a1.w, SCALE, -vv1.w);

        float m = x[0];
#pragma unroll
        for (int i = 1; i < 8; ++i) m = fmaxf(m, x[i]);
        m = wave_max(m);

        float e[8];
        float ls = 0.f;
#pragma unroll
        for (int i = 0; i < 8; ++i) { e[i] = __expf(x[i] - m); ls += e[i]; }
        float S = wave_sum(ls);

        if (lane == 0) { lm[r][w] = m; lsum[r][w] = S; }
        __syncthreads();

        const float m0 = lm[r][0], m1 = lm[r][1], m2 = lm[r][2], m3 = lm[r][3];
        const float M = fmaxf(fmaxf(m0, m1), fmaxf(m2, m3));
        const float T = lsum[r][0] * __expf(m0 - M) + lsum[r][1] * __expf(m1 - M)
                      + lsum[r][2] * __expf(m2 - M) + lsum[r][3] * __expf(m3 - M);
        if (threadIdx.x == 0) u[b * NN + row0 + r] = M + __logf(T);

        const float scale = __expf(m - M) * __builtin_amdgcn_rcpf(T);
#pragma unroll
        for (int i = 0; i < 8; ++i) s[i] = fmaf(e[i], scale, s[i]);

        a0 = na0; a1 = na1;
    }

    float4* pb = (float4*)(ps + (size_t)blockIdx.x * NN);
    pb[idx0] = make_float4(s[0], s[1], s[2], s[3]);
    pb[idx1] = make_float4(s[4], s[5], s[6], s[7]);
}

// v[c] += log( sum over CH chunks of ps[b][chunk][c] ).
// 512 blocks; block covers 32 cols x 8 chunk-groups; LDS combine.
__global__ __launch_bounds__(256) void combine(const float* __restrict__ ps,
                                               float* __restrict__ v) {
    const int coll = threadIdx.x & 31;
    const int grp  = threadIdx.x >> 5;           // 0..7
    const int gcol = blockIdx.x * 32 + coll;     // 0 .. NB*NN-1
    const int b    = gcol >> 11;
    const int col  = gcol & (NN - 1);
    const float* pb = ps + (size_t)b * CH * NN + col;

    float s0 = 0.f, s1 = 0.f, s2 = 0.f, s3 = 0.f;
#pragma unroll
    for (int i = 0; i < 32; i += 4) {
        const int c = (grp << 5) + i;
        s0 += pb[(size_t)(c + 0) * NN];
        s1 += pb[(size_t)(c + 1) * NN];
        s2 += pb[(size_t)(c + 2) * NN];
        s3 += pb[(size_t)(c + 3) * NN];
    }
    __shared__ float sm[8][33];
    sm[grp][coll] = (s0 + s1) + (s2 + s3);
    __syncthreads();
    if (threadIdx.x < 32) {
        float t = 0.f;
#pragma unroll
        for (int g = 0; g < 8; ++g) t += sm[g][threadIdx.x];
        v[gcol] += __logf(t);
    }
}

// ---------------- fallback path ----------------
__global__ __launch_bounds__(256) void row_lse(const float* __restrict__ A,
                                               const float* __restrict__ v,
                                               float* __restrict__ u) {
    const int wid  = threadIdx.x >> 6;
    const int lane = threadIdx.x & 63;
    const int row  = blockIdx.x * 4 + wid;
    const int b    = row >> 11;
    const float4* a4 = (const float4*)(A + (size_t)row * NN);
    const float4* v4 = (const float4*)(v + (size_t)b * NN);
    float x[32];
#pragma unroll
    for (int k = 0; k < 8; ++k) {
        float4 a  = a4[lane + (k << 6)];
        float4 vv = v4[lane + (k << 6)];
        x[4 * k + 0] = fmaf(a.x, SCALE, -vv.x);
        x[4 * k + 1] = fmaf(a.y, SCALE, -vv.y);
        x[4 * k + 2] = fmaf(a.z, SCALE, -vv.z);
        x[4 * k + 3] = fmaf(a.w, SCALE, -vv.w);
    }
    float m = -INFINITY;
#pragma unroll
    for (int i = 0; i < 32; ++i) m = fmaxf(m, x[i]);
    m = wave_max(m);
    float s = 0.f;
#pragma unroll
    for (int i = 0; i < 32; ++i) s += __expf(x[i] - m);
    s = wave_sum(s);
    if (lane == 0) u[row] = m + __logf(s);
}

__global__ __launch_bounds__(256) void col_lse(const float* __restrict__ A,
                                               const float* __restrict__ u,
                                               float* __restrict__ v) {
    const int b    = blockIdx.x >> 6;
    const int tile = blockIdx.x & 63;
    const int ci   = threadIdx.x & 31;
    const int rg   = threadIdx.x >> 5;
    const int col  = (tile << 5) + ci;
    const float* Ab = A + (size_t)b * NN * NN;
    const float* ub = u + b * NN;
    float m0 = -INFINITY, s0 = 0.f, m1 = -INFINITY, s1 = 0.f;
    for (int r = rg; r < NN; r += 16) {
        float x0 = fmaf(Ab[(size_t)r * NN + col], SCALE, -ub[r]);
        float x1 = fmaf(Ab[(size_t)(r + 8) * NN + col], SCALE, -ub[r + 8]);
        float nm0 = fmaxf(m0, x0);
        s0 = s0 * __expf(m0 - nm0) + __expf(x0 - nm0); m0 = nm0;
        float nm1 = fmaxf(m1, x1);
        s1 = s1 * __expf(m1 - nm1) + __expf(x1 - nm1); m1 = nm1;
    }
    float m = fmaxf(m0, m1);
    float s = s0 * __expf(m0 - m) + s1 * __expf(m1 - m);
    __shared__ float sm[8][33];
    __shared__ float ss[8][33];
    sm[rg][ci] = m; ss[rg][ci] = s;
    __syncthreads();
    if (threadIdx.x < 32) {
        const int c = threadIdx.x;
        float M = sm[0][c], S = ss[0][c];
#pragma unroll
        for (int g = 1; g < 8; ++g) {
            float mg = sm[g][c], sg = ss[g][c];
            float nM = fmaxf(M, mg);
            S = S * __expf(M - nM) + sg * __expf(mg - nM);
            M = nM;
        }
        v[b * NN + (tile << 5) + c] = M + __logf(S);
    }
}

// ---------------- final ----------------
// out = exp(A*SCALE - u[row] - v[col]); nontemporal stores keep A L3-resident.
__global__ __launch_bounds__(256) void final_exp(const float* __restrict__ A,
                                                 const float* __restrict__ u,
                                                 const float* __restrict__ v,
                                                 float* __restrict__ out) {
    const int i4    = blockIdx.x * 256 + threadIdx.x;
    const int rglob = i4 >> 9;
    const int c4    = i4 & 511;
    const int b     = rglob >> 11;
    const float uu  = u[rglob];
    float4 a  = ((const float4*)A)[i4];
    float4 vv = ((const float4*)(v + (size_t)b * NN))[c4];
    v4f o;
    o.x = __expf(fmaf(a.x, SCALE, -uu) - vv.x);
    o.y = __expf(fmaf(a.y, SCALE, -uu) - vv.y);
    o.z = __expf(fmaf(a.z, SCALE, -uu) - vv.z);
    o.w = __expf(fmaf(a.w, SCALE, -uu) - vv.w);
    __builtin_nontemporal_store(o, (v4f*)out + i4);
}

extern "C" void kernel_launch(void* const* d_in, const int* in_sizes, int n_in,
                              void* d_out, int out_size, void* d_ws, size_t ws_size,
                              hipStream_t stream) {
    const float* A = (const float*)d_in[0];
    float* out = (float*)d_out;
    float* u  = (float*)d_ws;                 // NB*NN floats
    float* v  = u + NB * NN;                  // NB*NN floats
    float* ps = v + NB * NN;                  // NB*CH*NN floats (fused path)

    const size_t need = ((size_t)2 * NB * NN + (size_t)NB * CH * NN) * sizeof(float);

    hipMemsetAsync(v, 0, NB * NN * sizeof(float), stream);

    if (ws_size >= need) {
        for (int it = 0; it < 10; ++it) {
            fused_iter<<<NB * CH, 256, 0, stream>>>(A, v, u, ps);
            combine<<<NB * NN / 32, 256, 0, stream>>>(ps, v);
        }
    } else {
        for (int it = 0; it < 10; ++it) {
            row_lse<<<NB * NN / 4, 256, 0, stream>>>(A, v, u);
            col_lse<<<NB * (NN / 32), 256, 0, stream>>>(A, u, v);
        }
    }
    final_exp<<<NB * NN * NN / 1024, 256, 0, stream>>>(A, u, v, out);
}